// Round 5
// baseline (434.418 us; speedup 1.0000x reference)
//
#include <hip/hip_runtime.h>
#include <hip/hip_bf16.h>
#include <cstdint>
#include <cstddef>

#define B_DIM 8
#define L_DIM 4096
#define D_INN 1024
#define H_DIM 1024
#define LATENTD 256
#define SEGLEN 128
#define KSUB 32
#define M_HALF (B_DIM * L_DIM)      // 32768
#define M_TOTAL (2 * M_HALF)        // 65536

typedef __attribute__((ext_vector_type(8))) short bf16x8;
typedef __attribute__((ext_vector_type(4))) float f32x4;

static __device__ __forceinline__ unsigned short f2bf(float x) {
  __hip_bfloat16 b = __float2bfloat16(x);
  return __builtin_bit_cast(unsigned short, b);
}

static __device__ __forceinline__ void async16(const unsigned short* g, unsigned short* l) {
  __builtin_amdgcn_global_load_lds(
      (const __attribute__((address_space(1))) unsigned int*)g,
      (__attribute__((address_space(3))) unsigned int*)l,
      16, 0, 0);
}

// ---------------- combined prep kernel ----------------
// grid (16,16,5):
//   z=0: WT  = transpose(W_proj)  (1024x1024 -> bf16)
//   z=1: WoutT = transpose(W_out) (1024x1024 -> bf16)
//   z=2: WcatT rows [0,256)   = transpose(W_mu) (1024x256)
//   z=3: WcatT rows [256,512) = transpose(W_lv)
//   z=4: decay vectors (only blocks y==0, x<4 active)
__global__ __launch_bounds__(256) void prep_kernel(const float* __restrict__ W_proj,
                                                   const float* __restrict__ a_raw,
                                                   const float* __restrict__ Wo,
                                                   const float* __restrict__ Wm,
                                                   const float* __restrict__ Wl,
                                                   unsigned short* __restrict__ WT,
                                                   float* __restrict__ avec,
                                                   float* __restrict__ gvec,
                                                   float* __restrict__ a128v,
                                                   unsigned short* __restrict__ WoutT,
                                                   unsigned short* __restrict__ WcatT) {
  const int z = blockIdx.z;
  if (z == 4) {
    if (blockIdx.y != 0 || blockIdx.x >= 4) return;
    int h = blockIdx.x * 256 + threadIdx.x;
    float a = 1.f / (1.f + expf(-a_raw[h]));
    float p = 1.f, g = 0.f;
    for (int j = 0; j < SEGLEN; j++) { g += p; p *= a; }
    avec[h] = a; gvec[h] = g; a128v[h] = p;   // p = a^128
    return;
  }
  __shared__ float tile[64][65];
  const float* src; unsigned short* dst; int N; int rowoff;
  if (z == 0)      { src = W_proj; dst = WT;    N = 1024; rowoff = 0; }
  else if (z == 1) { src = Wo;     dst = WoutT; N = 1024; rowoff = 0; }
  else if (z == 2) { src = Wm;     dst = WcatT; N = 256;  rowoff = 0; }
  else             { src = Wl;     dst = WcatT; N = 256;  rowoff = 256; }
  int k0 = blockIdx.x * 64, n0 = blockIdx.y * 64;
  if (n0 >= N) return;
  for (int i = threadIdx.x; i < 64 * 64; i += 256) {
    int kk = i >> 6, nn = i & 63;
    tile[kk][nn] = src[(size_t)(k0 + kk) * N + n0 + nn];
  }
  __syncthreads();
  for (int i = threadIdx.x; i < 64 * 64; i += 256) {
    int nn = i >> 6, kk = i & 63;
    dst[(size_t)(rowoff + n0 + nn) * 1024 + k0 + kk] = f2bf(tile[kk][nn]);
  }
}

// ---------------- main GEMM + segment decay reduction (fused fp32->bf16) ----
// Data path identical to R4 (verified): fp32 A reg-staged + converted +
// swizzled ds_write; B via global_load_lds with pre-swizzled source.
// SCHEDULE change (R4 post-mortem: sync-bound, MfmaUtil 30%): each K-tile is
// split into 4 phases of 16 MFMA (m201/T3 pattern), 4 barriers/tile, so the
// 8 waves phase-lock and one wave's ds_reads/stage-issue overlap other
// waves' MFMA. Staging discipline (T4, counted):
//   lock3 (all buf reads done) -> STAGEB(buf,t+2) -> MFMA_D
//   -> vmcnt(4) [in-order drain proves ALOAD(t+2) AND STAGEB(t+1) landed,
//      leaves only the 4 newest B-asyncs in flight] -> AWRITE -> ALOAD(t+3)
// Grid 1024 = 256 bm x 4 bn, XCD-chunked bijective swizzle.

__global__ __launch_bounds__(512) void gemm_seg_kernel(const float* __restrict__ Atgt,
                                                       const float* __restrict__ Adec,
                                                       const unsigned short* __restrict__ WT,
                                                       const float* __restrict__ avec,
                                                       const float* __restrict__ gvec,
                                                       const float* __restrict__ bproj,
                                                       float* __restrict__ Dred) {
  __shared__ alignas(16) unsigned short lds[65536];  // 128 KiB: A [0,32768), B [32768,65536)

  const int t = threadIdx.x;          // 0..511
  const int lane = t & 63;
  const int wave = t >> 6;            // 0..7
  const int wr = wave >> 2;           // 0..1  M-half (= segment within tile)
  const int wc = wave & 3;            // 0..3  N-quarter
  const int lo = lane & 15;
  const int q = lane >> 4;

  // XCD-chunked bijective swizzle: 1024 blocks = 8 XCDs * 128
  const int bid = blockIdx.x;
  const int w = (bid & 7) * 128 + (bid >> 3);
  const int bn = w & 3;               // 0..3   (fastest within XCD -> A-tile L2 reuse)
  const int bm = w >> 2;              // 0..255

  // ---- B staging (global_load_lds, pre-swizzled source) ----
  const int tr = t >> 3;                                  // row-within-64
  const int csw = (((t & 7) ^ (tr & 7)) * 8);             // pre-swizzled col (shorts)
  const unsigned short* Bsrc = WT + ((size_t)(bn * 256 + tr)) * 1024 + csw;
  unsigned short* ldsB = lds + 32768 + t * 8;

#define STAGEB(buf_, tile_)                                                        \
  {                                                                                \
    _Pragma("unroll")                                                              \
    for (int hl = 0; hl < 4; ++hl) {                                               \
      const int half_ = hl >> 1, l_ = hl & 1;                                      \
      async16(Bsrc + (size_t)(half_ * 128 + l_ * 64) * 1024 + (tile_) * 64,        \
              ldsB + (buf_) * 16384 + half_ * 8192 + l_ * 4096);                   \
    }                                                                              \
  }

  // ---- A reg-staging (fused fp32 read + convert) ----
  const float* Afp = ((bm < 128) ? Atgt : Adec) + ((size_t)(bm & 127)) * 256 * 1024;
  const float* Ath = Afp + ((size_t)(t >> 4)) * 1024 + (t & 15) * 4;
  const int awr_swz = (((((t & 15) >> 1)) ^ ((t >> 4) & 7)) * 8) + (t & 1) * 4;
  unsigned short* ldsAw = lds + ((t >> 4) * 64) + awr_swz;

  float4 fA[8];

#define ALOAD(tile_)                                                               \
  {                                                                                \
    _Pragma("unroll")                                                              \
    for (int i_ = 0; i_ < 8; ++i_)                                                 \
      fA[i_] = *(const float4*)(Ath + (size_t)i_ * 32768 + (tile_) * 64);          \
  }

#define AWRITE(buf_)                                                               \
  {                                                                                \
    _Pragma("unroll")                                                              \
    for (int i_ = 0; i_ < 8; ++i_) {                                               \
      ushort4 o_;                                                                  \
      o_.x = f2bf(fA[i_].x); o_.y = f2bf(fA[i_].y);                                \
      o_.z = f2bf(fA[i_].z); o_.w = f2bf(fA[i_].w);                                \
      *(ushort4*)(ldsAw + (buf_) * 16384 + i_ * 2048) = o_;                        \
    }                                                                              \
  }

  // ---- ds_read addressing (swizzled; unchanged from verified R2-R4) ----
  const unsigned short* ArdB = lds + (size_t)(wr * 128 + lo) * 64;
  const unsigned short* BrdB = lds + 32768 + (size_t)(wc * 64 + lo) * 64;
  const int ch0 = ((q ^ (lo & 7)) * 8);        // k-slice 0 chunk (shorts)
  const int ch1 = (((4 + q) ^ (lo & 7)) * 8);  // k-slice 1 chunk (shorts)

  f32x4 acc[8][4];
#pragma unroll
  for (int i = 0; i < 8; i++)
#pragma unroll
    for (int j = 0; j < 4; j++) acc[i][j] = (f32x4){0.f, 0.f, 0.f, 0.f};

#define PHASE_MFMA(aP_, bP_, i0_)                                                  \
  __builtin_amdgcn_s_setprio(1);                                                   \
  _Pragma("unroll")                                                                \
  for (int ii = 0; ii < 4; ++ii)                                                   \
    _Pragma("unroll")                                                              \
    for (int j = 0; j < 4; ++j)                                                    \
      acc[(i0_) + ii][j] =                                                         \
          __builtin_amdgcn_mfma_f32_16x16x32_bf16(aP_[ii], bP_[j],                 \
                                                  acc[(i0_) + ii][j], 0, 0, 0);    \
  __builtin_amdgcn_s_setprio(0);

  // ---- prologue: buf0<-tile0, buf1<-tile1, regs<-tile2 in flight ----
  ALOAD(0);
  __builtin_amdgcn_sched_barrier(0);
  STAGEB(0, 0);
  STAGEB(1, 1);
  __builtin_amdgcn_sched_barrier(0);
  asm volatile("s_waitcnt vmcnt(8)" ::: "memory");   // ALOAD(0) landed (8 newest = B asyncs)
  AWRITE(0);
  ALOAD(1);
  __builtin_amdgcn_sched_barrier(0);
  asm volatile("s_waitcnt vmcnt(0)" ::: "memory");   // ALOAD(1) + all B landed
  AWRITE(1);
  ALOAD(2);                                          // flies across tile 0
  __builtin_amdgcn_sched_barrier(0);
  asm volatile("s_waitcnt lgkmcnt(0)" ::: "memory");
  __builtin_amdgcn_sched_barrier(0);

  int buf = 0;
  for (int tile = 0; tile < 16; ++tile) {
    if (tile == 15) asm volatile("s_waitcnt vmcnt(0)" ::: "memory");
    asm volatile("s_barrier" ::: "memory");          // top: publish buf
    __builtin_amdgcn_sched_barrier(0);

    const unsigned short* Ab = ArdB + buf * 16384;
    const unsigned short* Bb = BrdB + buf * 16384;

    bf16x8 aA[4], aB[4], aC[4], aD[4], bv0[4], bv1[4];

    // ---- phase A: rows 0-3 x k0 ----
#pragma unroll
    for (int ii = 0; ii < 4; ++ii) aA[ii] = *(const bf16x8*)&Ab[ii * 1024 + ch0];
#pragma unroll
    for (int j = 0; j < 4; ++j) bv0[j] = *(const bf16x8*)&Bb[j * 1024 + ch0];
    asm volatile("s_waitcnt lgkmcnt(0)" ::: "memory");
    __builtin_amdgcn_sched_barrier(0);
    PHASE_MFMA(aA, bv0, 0)
    __builtin_amdgcn_sched_barrier(0);

    // ---- phase B: rows 4-7 x k0 (reads fly during other waves' MFMA_A) ----
#pragma unroll
    for (int ii = 0; ii < 4; ++ii) aB[ii] = *(const bf16x8*)&Ab[(4 + ii) * 1024 + ch0];
    asm volatile("s_barrier" ::: "memory");          // lock 1
    asm volatile("s_waitcnt lgkmcnt(0)" ::: "memory");
    __builtin_amdgcn_sched_barrier(0);
    PHASE_MFMA(aB, bv0, 4)
    __builtin_amdgcn_sched_barrier(0);

    // ---- phase C: rows 0-3 x k1 ----
#pragma unroll
    for (int ii = 0; ii < 4; ++ii) aC[ii] = *(const bf16x8*)&Ab[ii * 1024 + ch1];
#pragma unroll
    for (int j = 0; j < 4; ++j) bv1[j] = *(const bf16x8*)&Bb[j * 1024 + ch1];
    asm volatile("s_barrier" ::: "memory");          // lock 2
    asm volatile("s_waitcnt lgkmcnt(0)" ::: "memory");
    __builtin_amdgcn_sched_barrier(0);
    PHASE_MFMA(aC, bv1, 0)
    __builtin_amdgcn_sched_barrier(0);

    // ---- phase D: rows 4-7 x k1 ----
#pragma unroll
    for (int ii = 0; ii < 4; ++ii) aD[ii] = *(const bf16x8*)&Ab[(4 + ii) * 1024 + ch1];
    asm volatile("s_waitcnt lgkmcnt(0)" ::: "memory");  // own buf reads complete
    __builtin_amdgcn_sched_barrier(0);
    asm volatile("s_barrier" ::: "memory");          // lock 3: ALL waves done reading buf
    __builtin_amdgcn_sched_barrier(0);

    if (tile < 14) STAGEB(buf, tile + 2);            // clobber-safe; overlaps MFMA_D

    PHASE_MFMA(aD, bv1, 4)
    __builtin_amdgcn_sched_barrier(0);

    if (tile < 14) {
      // outstanding (oldest->newest): [STAGEB(t+1)] [ALOAD(t+2) x8] [STAGEB(t+2) x4]
      // vmcnt(4): in-order drain -> ALOAD(t+2) AND STAGEB(t+1) proven landed;
      // only the 4 newest B-asyncs stay in flight across the next tile.
      asm volatile("s_waitcnt vmcnt(4)" ::: "memory");
      __builtin_amdgcn_sched_barrier(0);
      AWRITE(buf);                   // cvt + conflict-free swizzled ds_write
      if (tile < 13) ALOAD(tile + 3);  // regs free -> next A flies a FULL tile
      __builtin_amdgcn_sched_barrier(0);
    }
    buf ^= 1;
  }
#undef STAGEB
#undef ALOAD
#undef AWRITE
#undef PHASE_MFMA

  // ---- epilogue: per-wave Horner decay reduction, one segment per wave ----
  // weight(acc[i][j][r]) must be a^(127-row), row = i*16 + q*4 + r.
  // Horner gives a^(115-16i-r); correction qf = a^(12-4q).
  const int seg = bm * 2 + wr;
#pragma unroll
  for (int j = 0; j < 4; ++j) {
    const int h = bn * 256 + wc * 64 + j * 16 + lo;
    const float a = avec[h];
    const float a2 = a * a, a4 = a2 * a2, a8 = a4 * a4, a16 = a8 * a8;
    float P = 0.f;
#pragma unroll
    for (int i = 0; i < 8; ++i) {
      f32x4 u = acc[i][j];
      float vi = ((u.x * a + u.y) * a + u.z) * a + u.w;
      P = P * a16 + vi;
    }
    const float qf = (q == 3) ? 1.f : ((q == 2) ? a4 : ((q == 1) ? a8 : a8 * a4));
    P *= qf;
    P += __shfl_xor(P, 16);
    P += __shfl_xor(P, 32);
    if (q == 0)
      Dred[(size_t)seg * H_DIM + h] = P + bproj[h] * gvec[h];
  }
}

// ---------------- prefix scan over k + hT (bf16 out) ----------------
__global__ __launch_bounds__(256) void state_kernel(const float* __restrict__ Dred,
                                                    const float* __restrict__ a128v,
                                                    unsigned short* __restrict__ hTbf) {
  int idx = blockIdx.x * 256 + threadIdx.x;  // b*1024 + h, 8192 total
  int b = idx >> 10, h = idx & 1023;
  const float* S = Dred + (size_t)b * KSUB * H_DIM + h;            // corr stream
  const float* Dd = Dred + (size_t)(B_DIM + b) * KSUB * H_DIM + h; // dec stream
  float A = a128v[h];
  float C = 0.f;
  for (int k = 0; k < KSUB; k++) {
    hTbf[((size_t)(b * KSUB + k)) * H_DIM + h] = f2bf(fmaf(A, C, Dd[(size_t)k * H_DIM]));
    C = fmaf(A, C, S[(size_t)k * H_DIM]);
  }
}

// ---------------- MFMA heads ----------------
// head1: y = silu(hT @ W_out + b_out)   M=256, N=1024, K=1024, out bf16
__global__ __launch_bounds__(256) void head1_kernel(const unsigned short* __restrict__ Abf,
                                                    const unsigned short* __restrict__ Bt,
                                                    const float* __restrict__ bias,
                                                    unsigned short* __restrict__ ybf) {
  __shared__ alignas(16) unsigned short As[128 * 32];
  __shared__ alignas(16) unsigned short Bs[128 * 32];
  const int t = threadIdx.x;
  const int lane = t & 63, wave = t >> 6;
  const int bm = blockIdx.x, bn = blockIdx.y;
  const int lo = lane & 15, q = lane >> 4;
  const int wm = wave & 1, wn = wave >> 1;

  f32x4 acc[4][4];
#pragma unroll
  for (int i = 0; i < 4; i++)
#pragma unroll
    for (int j = 0; j < 4; j++) acc[i][j] = (f32x4){0.f, 0.f, 0.f, 0.f};

  const int r0 = t >> 2;
  const int c0 = (t & 3) * 8;
  const unsigned short* Ag0 = Abf + ((size_t)bm * 128 + r0) * 1024 + c0;
  const unsigned short* Ag1 = Abf + ((size_t)bm * 128 + 64 + r0) * 1024 + c0;
  const unsigned short* Bg0 = Bt + ((size_t)bn * 128 + r0) * 1024 + c0;
  const unsigned short* Bg1 = Bt + ((size_t)bn * 128 + 64 + r0) * 1024 + c0;
  unsigned short* Al0 = &As[t * 8];
  unsigned short* Al1 = &As[(256 + t) * 8];
  unsigned short* Bl0 = &Bs[t * 8];
  unsigned short* Bl1 = &Bs[(256 + t) * 8];

  for (int kk = 0; kk < 1024; kk += 32) {
    async16(Ag0 + kk, Al0);
    async16(Ag1 + kk, Al1);
    async16(Bg0 + kk, Bl0);
    async16(Bg1 + kk, Bl1);
    __syncthreads();
    bf16x8 af[4], bv[4];
#pragma unroll
    for (int i = 0; i < 4; i++)
      af[i] = *(const bf16x8*)&As[(wm * 64 + i * 16 + lo) * 32 + q * 8];
#pragma unroll
    for (int j = 0; j < 4; j++)
      bv[j] = *(const bf16x8*)&Bs[(wn * 64 + j * 16 + lo) * 32 + q * 8];
#pragma unroll
    for (int i = 0; i < 4; i++)
#pragma unroll
      for (int j = 0; j < 4; j++)
        acc[i][j] = __builtin_amdgcn_mfma_f32_16x16x32_bf16(af[i], bv[j], acc[i][j], 0, 0, 0);
    __syncthreads();
  }

#pragma unroll
  for (int j = 0; j < 4; j++) {
    const int col = bn * 128 + wn * 64 + j * 16 + lo;
    const float bb = bias[col];
#pragma unroll
    for (int i = 0; i < 4; i++) {
#pragma unroll
      for (int r = 0; r < 4; r++) {
        const int row = bm * 128 + wm * 64 + i * 16 + q * 4 + r;
        float z = acc[i][j][r] + bb;
        float y = z / (1.f + expf(-z));
        ybf[(size_t)row * 1024 + col] = f2bf(y);
      }
    }
  }
}

// head2: [mu|lv] = y @ [W_mu|W_lv] + [b_mu|b_lv]   M=256, N=512, K=1024, out fp32
__global__ __launch_bounds__(256) void head2_kernel(const unsigned short* __restrict__ Abf,
                                                    const unsigned short* __restrict__ Bt,
                                                    const float* __restrict__ bmu,
                                                    const float* __restrict__ blv,
                                                    float* __restrict__ out) {
  __shared__ alignas(16) unsigned short As[128 * 32];
  __shared__ alignas(16) unsigned short Bs[128 * 32];
  const int t = threadIdx.x;
  const int lane = t & 63, wave = t >> 6;
  const int bm = blockIdx.x, bn = blockIdx.y;   // bn 0..3
  const int lo = lane & 15, q = lane >> 4;
  const int wm = wave & 1, wn = wave >> 1;

  f32x4 acc[4][4];
#pragma unroll
  for (int i = 0; i < 4; i++)
#pragma unroll
    for (int j = 0; j < 4; j++) acc[i][j] = (f32x4){0.f, 0.f, 0.f, 0.f};

  const int r0 = t >> 2;
  const int c0 = (t & 3) * 8;
  const unsigned short* Ag0 = Abf + ((size_t)bm * 128 + r0) * 1024 + c0;
  const unsigned short* Ag1 = Abf + ((size_t)bm * 128 + 64 + r0) * 1024 + c0;
  const unsigned short* Bg0 = Bt + ((size_t)bn * 128 + r0) * 1024 + c0;
  const unsigned short* Bg1 = Bt + ((size_t)bn * 128 + 64 + r0) * 1024 + c0;
  unsigned short* Al0 = &As[t * 8];
  unsigned short* Al1 = &As[(256 + t) * 8];
  unsigned short* Bl0 = &Bs[t * 8];
  unsigned short* Bl1 = &Bs[(256 + t) * 8];

  for (int kk = 0; kk < 1024; kk += 32) {
    async16(Ag0 + kk, Al0);
    async16(Ag1 + kk, Al1);
    async16(Bg0 + kk, Bl0);
    async16(Bg1 + kk, Bl1);
    __syncthreads();
    bf16x8 af[4], bv[4];
#pragma unroll
    for (int i = 0; i < 4; i++)
      af[i] = *(const bf16x8*)&As[(wm * 64 + i * 16 + lo) * 32 + q * 8];
#pragma unroll
    for (int j = 0; j < 4; j++)
      bv[j] = *(const bf16x8*)&Bs[(wn * 64 + j * 16 + lo) * 32 + q * 8];
#pragma unroll
    for (int i = 0; i < 4; i++)
#pragma unroll
      for (int j = 0; j < 4; j++)
        acc[i][j] = __builtin_amdgcn_mfma_f32_16x16x32_bf16(af[i], bv[j], acc[i][j], 0, 0, 0);
    __syncthreads();
  }

#pragma unroll
  for (int j = 0; j < 4; j++) {
    const int col = bn * 128 + wn * 64 + j * 16 + lo;   // 0..511
    const float bb = (col < 256) ? bmu[col] : blv[col - 256];
    float* dst = (col < 256) ? (out + col) : (out + 65536 + (col - 256));
#pragma unroll
    for (int i = 0; i < 4; i++) {
#pragma unroll
      for (int r = 0; r < 4; r++) {
        const int row = bm * 128 + wm * 64 + i * 16 + q * 4 + r;
        dst[(size_t)row * 256] = acc[i][j][r] + bb;
      }
    }
  }
}

// ---------------- launcher ----------------
extern "C" void kernel_launch(void* const* d_in, const int* in_sizes, int n_in,
                              void* d_out, int out_size, void* d_ws, size_t ws_size,
                              hipStream_t stream) {
  const float* decoder = (const float*)d_in[0];
  const float* targets = (const float*)d_in[1];
  const float* W_proj = (const float*)d_in[2];
  const float* b_proj = (const float*)d_in[3];
  const float* a_raw = (const float*)d_in[4];
  const float* W_out = (const float*)d_in[5];
  const float* b_out = (const float*)d_in[6];
  const float* W_mu = (const float*)d_in[7];
  const float* b_mu = (const float*)d_in[8];
  const float* W_lv = (const float*)d_in[9];
  const float* b_lv = (const float*)d_in[10];
  float* out = (float*)d_out;

  char* ws = (char*)d_ws;
  unsigned short* WT = (unsigned short*)(ws + 134217728);         // 2097152 B
  float* avec = (float*)(ws + 136314880);                         // 4096 B
  float* gvec = (float*)(ws + 136318976);                         // 4096 B
  float* a128v = (float*)(ws + 136323072);                        // 4096 B
  float* DredP = (float*)(ws + 136327168);                        // 2097152 B -> end 138424320
  // low workspace region:
  unsigned short* hTbf = (unsigned short*)ws;                     // 524288 B
  unsigned short* ybf = (unsigned short*)(ws + 524288);           // 524288 B
  unsigned short* WoutT = (unsigned short*)(ws + 1048576);        // 2097152 B
  unsigned short* WcatT = (unsigned short*)(ws + 3145728);        // 1048576 B

  prep_kernel<<<dim3(16, 16, 5), 256, 0, stream>>>(W_proj, a_raw, W_out, W_mu, W_lv,
                                                   WT, avec, gvec, a128v, WoutT, WcatT);
  gemm_seg_kernel<<<1024, 512, 0, stream>>>(targets, decoder, WT, avec, gvec, b_proj, DredP);
  state_kernel<<<32, 256, 0, stream>>>(DredP, a128v, hTbf);
  head1_kernel<<<dim3(2, 8), 256, 0, stream>>>(hTbf, WoutT, b_out, ybf);
  head2_kernel<<<dim3(2, 4), 256, 0, stream>>>(ybf, WcatT, b_mu, b_lv, out);
}

// Round 6
// 424.903 us; speedup vs baseline: 1.0224x; 1.0224x over previous
//
#include <hip/hip_runtime.h>
#include <hip/hip_bf16.h>
#include <cstdint>
#include <cstddef>

#define B_DIM 8
#define L_DIM 4096
#define D_INN 1024
#define H_DIM 1024
#define LATENTD 256
#define SEGLEN 128
#define KSUB 32
#define M_HALF (B_DIM * L_DIM)      // 32768
#define M_TOTAL (2 * M_HALF)        // 65536

typedef __attribute__((ext_vector_type(8))) short bf16x8;
typedef __attribute__((ext_vector_type(4))) float f32x4;

static __device__ __forceinline__ unsigned short f2bf(float x) {
  __hip_bfloat16 b = __float2bfloat16(x);
  return __builtin_bit_cast(unsigned short, b);
}

static __device__ __forceinline__ void async16(const unsigned short* g, unsigned short* l) {
  __builtin_amdgcn_global_load_lds(
      (const __attribute__((address_space(1))) unsigned int*)g,
      (__attribute__((address_space(3))) unsigned int*)l,
      16, 0, 0);
}

// ---------------- combined prep kernel ----------------
// grid (16,16,5):
//   z=0: WT  = transpose(W_proj)  (1024x1024 -> bf16)
//   z=1: WoutT = transpose(W_out) (1024x1024 -> bf16)
//   z=2: WcatT rows [0,256)   = transpose(W_mu) (1024x256)
//   z=3: WcatT rows [256,512) = transpose(W_lv)
//   z=4: decay vectors (only blocks y==0, x<4 active)
__global__ __launch_bounds__(256) void prep_kernel(const float* __restrict__ W_proj,
                                                   const float* __restrict__ a_raw,
                                                   const float* __restrict__ Wo,
                                                   const float* __restrict__ Wm,
                                                   const float* __restrict__ Wl,
                                                   unsigned short* __restrict__ WT,
                                                   float* __restrict__ avec,
                                                   float* __restrict__ gvec,
                                                   float* __restrict__ a128v,
                                                   unsigned short* __restrict__ WoutT,
                                                   unsigned short* __restrict__ WcatT) {
  const int z = blockIdx.z;
  if (z == 4) {
    if (blockIdx.y != 0 || blockIdx.x >= 4) return;
    int h = blockIdx.x * 256 + threadIdx.x;
    float a = 1.f / (1.f + expf(-a_raw[h]));
    float p = 1.f, g = 0.f;
    for (int j = 0; j < SEGLEN; j++) { g += p; p *= a; }
    avec[h] = a; gvec[h] = g; a128v[h] = p;   // p = a^128
    return;
  }
  __shared__ float tile[64][65];
  const float* src; unsigned short* dst; int N; int rowoff;
  if (z == 0)      { src = W_proj; dst = WT;    N = 1024; rowoff = 0; }
  else if (z == 1) { src = Wo;     dst = WoutT; N = 1024; rowoff = 0; }
  else if (z == 2) { src = Wm;     dst = WcatT; N = 256;  rowoff = 0; }
  else             { src = Wl;     dst = WcatT; N = 256;  rowoff = 256; }
  int k0 = blockIdx.x * 64, n0 = blockIdx.y * 64;
  if (n0 >= N) return;
  for (int i = threadIdx.x; i < 64 * 64; i += 256) {
    int kk = i >> 6, nn = i & 63;
    tile[kk][nn] = src[(size_t)(k0 + kk) * N + n0 + nn];
  }
  __syncthreads();
  for (int i = threadIdx.x; i < 64 * 64; i += 256) {
    int nn = i >> 6, kk = i & 63;
    dst[(size_t)(rowoff + n0 + nn) * 1024 + k0 + kk] = f2bf(tile[kk][nn]);
  }
}

// ---------------- main GEMM + segment decay reduction (persistent) ----------
// PERSISTENT-BLOCK version (R5 post-mortem: fill/drain-bound, phases neutral).
// Grid = 256 blocks (1/CU, all resident). Each block runs FOUR former
// work-items as one continuous 64-tile pipeline: prologue once, dbuf never
// drains between items, per-item epilogue (Horner+shfl+4 stores+acc reset)
// overlaps in-flight staging. Mapping (bijective, XCD-preserving):
//   x=bid&7 (XCD), c=bid>>3: bn=c&3 (fixed/block), bm(it)=32x+(c>>2)+8it
//   -> XCD x owns bm[32x,32x+32) for all bn, same as rounds 1-5.
// A-source select (targets vs decoder) is fixed per block (x<4 <-> bm<128).
// Body = R4's verified 2-barrier schedule; A fp32 reg-staged with full-tile
// prefetch distance; counted vmcnt(4) drains exactly the A loads (epilogue
// loads/stores are older than the newest STAGEB -> counting stays exact).

__global__ __launch_bounds__(512) void gemm_seg_kernel(const float* __restrict__ Atgt,
                                                       const float* __restrict__ Adec,
                                                       const unsigned short* __restrict__ WT,
                                                       const float* __restrict__ avec,
                                                       const float* __restrict__ gvec,
                                                       const float* __restrict__ bproj,
                                                       float* __restrict__ Dred) {
  __shared__ alignas(16) unsigned short lds[65536];  // 128 KiB: A [0,32768), B [32768,65536)

  const int t = threadIdx.x;          // 0..511
  const int lane = t & 63;
  const int wave = t >> 6;            // 0..7
  const int wr = wave >> 2;           // 0..1  M-half (= segment within tile)
  const int wc = wave & 3;            // 0..3  N-quarter
  const int lo = lane & 15;
  const int q = lane >> 4;

  const int bid = blockIdx.x;         // 0..255
  const int bn = (bid >> 3) & 3;                          // fixed per block
  const int bm0 = ((bid & 7) * 128 + (bid >> 3)) >> 2;    // item 0's bm; bm(it)=bm0+8it

  // ---- B staging (global_load_lds, pre-swizzled source; depends on kk only) ----
  const int tr = t >> 3;                                  // row-within-64
  const int csw = (((t & 7) ^ (tr & 7)) * 8);             // pre-swizzled col (shorts)
  const unsigned short* Bsrc = WT + ((size_t)(bn * 256 + tr)) * 1024 + csw;
  unsigned short* ldsB = lds + 32768 + t * 8;

#define STAGEB(buf_, gt_)                                                          \
  {                                                                                \
    _Pragma("unroll")                                                              \
    for (int hl = 0; hl < 4; ++hl) {                                               \
      const int half_ = hl >> 1, l_ = hl & 1;                                      \
      async16(Bsrc + (size_t)(half_ * 128 + l_ * 64) * 1024 + ((gt_) & 15) * 64,   \
              ldsB + (buf_) * 16384 + half_ * 8192 + l_ * 4096);                   \
    }                                                                              \
  }

  // ---- A reg-staging (fused fp32 read + convert) ----
  // Ath = item-0 base; item step = 8 bm * 256 rows * 1024 cols = 2097152 floats.
  const float* Afp = ((bm0 < 128) ? Atgt : Adec) + ((size_t)(bm0 & 127)) * 256 * 1024;
  const float* Ath = Afp + ((size_t)(t >> 4)) * 1024 + (t & 15) * 4;
  const int awr_swz = (((((t & 15) >> 1)) ^ ((t >> 4) & 7)) * 8) + (t & 1) * 4;
  unsigned short* ldsAw = lds + ((t >> 4) * 64) + awr_swz;

  float4 fA[8];

#define ALOAD(gt_)                                                                 \
  {                                                                                \
    _Pragma("unroll")                                                              \
    for (int i_ = 0; i_ < 8; ++i_)                                                 \
      fA[i_] = *(const float4*)(Ath + (size_t)i_ * 32768 +                         \
                                (size_t)((gt_) >> 4) * 2097152 + ((gt_) & 15) * 64); \
  }

#define AWRITE(buf_)                                                               \
  {                                                                                \
    _Pragma("unroll")                                                              \
    for (int i_ = 0; i_ < 8; ++i_) {                                               \
      ushort4 o_;                                                                  \
      o_.x = f2bf(fA[i_].x); o_.y = f2bf(fA[i_].y);                                \
      o_.z = f2bf(fA[i_].z); o_.w = f2bf(fA[i_].w);                                \
      *(ushort4*)(ldsAw + (buf_) * 16384 + i_ * 2048) = o_;                        \
    }                                                                              \
  }

  // ---- ds_read addressing (swizzled; unchanged from verified R2-R5) ----
  const unsigned short* ArdB = lds + (size_t)(wr * 128 + lo) * 64;
  const unsigned short* BrdB = lds + 32768 + (size_t)(wc * 64 + lo) * 64;
  const int ch0 = ((q ^ (lo & 7)) * 8);        // k-slice 0 chunk (shorts)
  const int ch1 = (((4 + q) ^ (lo & 7)) * 8);  // k-slice 1 chunk (shorts)

  f32x4 acc[8][4];
#pragma unroll
  for (int i = 0; i < 8; i++)
#pragma unroll
    for (int j = 0; j < 4; j++) acc[i][j] = (f32x4){0.f, 0.f, 0.f, 0.f};

  // ---- prologue (once per block): buf0<-gt0, buf1<-gt1, regs<-gt2 in flight ----
  ALOAD(0);
  __builtin_amdgcn_sched_barrier(0);
  STAGEB(0, 0);
  STAGEB(1, 1);
  __builtin_amdgcn_sched_barrier(0);
  asm volatile("s_waitcnt vmcnt(8)" ::: "memory");   // ALOAD(0) landed (8 newest = B asyncs)
  AWRITE(0);
  ALOAD(1);
  __builtin_amdgcn_sched_barrier(0);
  asm volatile("s_waitcnt vmcnt(0)" ::: "memory");   // ALOAD(1) + all B landed
  AWRITE(1);
  ALOAD(2);                                          // flies across gt 0
  __builtin_amdgcn_sched_barrier(0);
  asm volatile("s_waitcnt lgkmcnt(0)" ::: "memory");
  __builtin_amdgcn_sched_barrier(0);

  int buf = 0;
  for (int gt = 0; gt < 64; ++gt) {                  // 4 items x 16 K-tiles, continuous
    if (gt == 63) asm volatile("s_waitcnt vmcnt(0)" ::: "memory");
    asm volatile("s_barrier" ::: "memory");          // top: publish buf
    __builtin_amdgcn_sched_barrier(0);

    const unsigned short* Ab = ArdB + buf * 16384;
    const unsigned short* Bb = BrdB + buf * 16384;

    bf16x8 a0[8], b0[4];
#pragma unroll
    for (int i = 0; i < 8; i++) a0[i] = *(const bf16x8*)&Ab[i * 1024 + ch0];
#pragma unroll
    for (int j = 0; j < 4; j++) b0[j] = *(const bf16x8*)&Bb[j * 1024 + ch0];
#pragma unroll
    for (int i = 0; i < 8; i++)
#pragma unroll
      for (int j = 0; j < 4; j++)
        acc[i][j] = __builtin_amdgcn_mfma_f32_16x16x32_bf16(a0[i], b0[j], acc[i][j], 0, 0, 0);

    bf16x8 a1[8], b1[4];
#pragma unroll
    for (int i = 0; i < 8; i++) a1[i] = *(const bf16x8*)&Ab[i * 1024 + ch1];
#pragma unroll
    for (int j = 0; j < 4; j++) b1[j] = *(const bf16x8*)&Bb[j * 1024 + ch1];

    // all LDS reads of this buffer done (per-wave), then workgroup-wide
    asm volatile("s_waitcnt lgkmcnt(0)" ::: "memory");
    __builtin_amdgcn_sched_barrier(0);
    asm volatile("s_barrier" ::: "memory");

    if (gt < 62) STAGEB(buf, gt + 2);                // clobber-safe: all past buf reads

    __builtin_amdgcn_s_setprio(1);
#pragma unroll
    for (int i = 0; i < 8; i++)
#pragma unroll
      for (int j = 0; j < 4; j++)
        acc[i][j] = __builtin_amdgcn_mfma_f32_16x16x32_bf16(a1[i], b1[j], acc[i][j], 0, 0, 0);
    __builtin_amdgcn_s_setprio(0);
    __builtin_amdgcn_sched_barrier(0);

    if (gt < 62) {
      // outstanding (oldest->newest): [STAGEB(gt+1)] [ALOAD(gt+2) x8] [STAGEB(gt+2) x4]
      // (+ possibly older epilogue loads/stores, all drained too)
      // vmcnt(4): leaves only the 4 newest B-asyncs in flight.
      asm volatile("s_waitcnt vmcnt(4)" ::: "memory");
      __builtin_amdgcn_sched_barrier(0);
      AWRITE(buf);                   // cvt + conflict-free swizzled ds_write
      if (gt < 61) ALOAD(gt + 3);    // regs free -> next A flies a FULL tile
      __builtin_amdgcn_sched_barrier(0);
      asm volatile("s_waitcnt lgkmcnt(0)" ::: "memory");  // AWRITE visible before top barrier
      __builtin_amdgcn_sched_barrier(0);
    }

    // ---- per-item epilogue at gt&15==15: Horner decay reduce, store, reset ----
    if ((gt & 15) == 15) {
      const int itv = gt >> 4;
      const int seg = (bm0 + 8 * itv) * 2 + wr;
#pragma unroll
      for (int j = 0; j < 4; ++j) {
        const int h = bn * 256 + wc * 64 + j * 16 + lo;
        const float a = avec[h];
        const float a2 = a * a, a4 = a2 * a2, a8 = a4 * a4, a16 = a8 * a8;
        float P = 0.f;
#pragma unroll
        for (int i = 0; i < 8; ++i) {
          f32x4 u = acc[i][j];
          float vi = ((u.x * a + u.y) * a + u.z) * a + u.w;
          P = P * a16 + vi;
        }
        const float qf = (q == 3) ? 1.f : ((q == 2) ? a4 : ((q == 1) ? a8 : a8 * a4));
        P *= qf;
        P += __shfl_xor(P, 16);
        P += __shfl_xor(P, 32);
        if (q == 0)
          Dred[(size_t)seg * H_DIM + h] = P + bproj[h] * gvec[h];
      }
#pragma unroll
      for (int i = 0; i < 8; i++)
#pragma unroll
        for (int j = 0; j < 4; j++) acc[i][j] = (f32x4){0.f, 0.f, 0.f, 0.f};
    }
    buf ^= 1;
  }
#undef STAGEB
#undef ALOAD
#undef AWRITE
}

// ---------------- prefix scan over k + hT (bf16 out) ----------------
__global__ __launch_bounds__(256) void state_kernel(const float* __restrict__ Dred,
                                                    const float* __restrict__ a128v,
                                                    unsigned short* __restrict__ hTbf) {
  int idx = blockIdx.x * 256 + threadIdx.x;  // b*1024 + h, 8192 total
  int b = idx >> 10, h = idx & 1023;
  const float* S = Dred + (size_t)b * KSUB * H_DIM + h;            // corr stream
  const float* Dd = Dred + (size_t)(B_DIM + b) * KSUB * H_DIM + h; // dec stream
  float A = a128v[h];
  float C = 0.f;
  for (int k = 0; k < KSUB; k++) {
    hTbf[((size_t)(b * KSUB + k)) * H_DIM + h] = f2bf(fmaf(A, C, Dd[(size_t)k * H_DIM]));
    C = fmaf(A, C, S[(size_t)k * H_DIM]);
  }
}

// ---------------- MFMA heads ----------------
// head1: y = silu(hT @ W_out + b_out)   M=256, N=1024, K=1024, out bf16
__global__ __launch_bounds__(256) void head1_kernel(const unsigned short* __restrict__ Abf,
                                                    const unsigned short* __restrict__ Bt,
                                                    const float* __restrict__ bias,
                                                    unsigned short* __restrict__ ybf) {
  __shared__ alignas(16) unsigned short As[128 * 32];
  __shared__ alignas(16) unsigned short Bs[128 * 32];
  const int t = threadIdx.x;
  const int lane = t & 63, wave = t >> 6;
  const int bm = blockIdx.x, bn = blockIdx.y;
  const int lo = lane & 15, q = lane >> 4;
  const int wm = wave & 1, wn = wave >> 1;

  f32x4 acc[4][4];
#pragma unroll
  for (int i = 0; i < 4; i++)
#pragma unroll
    for (int j = 0; j < 4; j++) acc[i][j] = (f32x4){0.f, 0.f, 0.f, 0.f};

  const int r0 = t >> 2;
  const int c0 = (t & 3) * 8;
  const unsigned short* Ag0 = Abf + ((size_t)bm * 128 + r0) * 1024 + c0;
  const unsigned short* Ag1 = Abf + ((size_t)bm * 128 + 64 + r0) * 1024 + c0;
  const unsigned short* Bg0 = Bt + ((size_t)bn * 128 + r0) * 1024 + c0;
  const unsigned short* Bg1 = Bt + ((size_t)bn * 128 + 64 + r0) * 1024 + c0;
  unsigned short* Al0 = &As[t * 8];
  unsigned short* Al1 = &As[(256 + t) * 8];
  unsigned short* Bl0 = &Bs[t * 8];
  unsigned short* Bl1 = &Bs[(256 + t) * 8];

  for (int kk = 0; kk < 1024; kk += 32) {
    async16(Ag0 + kk, Al0);
    async16(Ag1 + kk, Al1);
    async16(Bg0 + kk, Bl0);
    async16(Bg1 + kk, Bl1);
    __syncthreads();
    bf16x8 af[4], bv[4];
#pragma unroll
    for (int i = 0; i < 4; i++)
      af[i] = *(const bf16x8*)&As[(wm * 64 + i * 16 + lo) * 32 + q * 8];
#pragma unroll
    for (int j = 0; j < 4; j++)
      bv[j] = *(const bf16x8*)&Bs[(wn * 64 + j * 16 + lo) * 32 + q * 8];
#pragma unroll
    for (int i = 0; i < 4; i++)
#pragma unroll
      for (int j = 0; j < 4; j++)
        acc[i][j] = __builtin_amdgcn_mfma_f32_16x16x32_bf16(af[i], bv[j], acc[i][j], 0, 0, 0);
    __syncthreads();
  }

#pragma unroll
  for (int j = 0; j < 4; j++) {
    const int col = bn * 128 + wn * 64 + j * 16 + lo;
    const float bb = bias[col];
#pragma unroll
    for (int i = 0; i < 4; i++) {
#pragma unroll
      for (int r = 0; r < 4; r++) {
        const int row = bm * 128 + wm * 64 + i * 16 + q * 4 + r;
        float z = acc[i][j][r] + bb;
        float y = z / (1.f + expf(-z));
        ybf[(size_t)row * 1024 + col] = f2bf(y);
      }
    }
  }
}

// head2: [mu|lv] = y @ [W_mu|W_lv] + [b_mu|b_lv]   M=256, N=512, K=1024, out fp32
__global__ __launch_bounds__(256) void head2_kernel(const unsigned short* __restrict__ Abf,
                                                    const unsigned short* __restrict__ Bt,
                                                    const float* __restrict__ bmu,
                                                    const float* __restrict__ blv,
                                                    float* __restrict__ out) {
  __shared__ alignas(16) unsigned short As[128 * 32];
  __shared__ alignas(16) unsigned short Bs[128 * 32];
  const int t = threadIdx.x;
  const int lane = t & 63, wave = t >> 6;
  const int bm = blockIdx.x, bn = blockIdx.y;   // bn 0..3
  const int lo = lane & 15, q = lane >> 4;
  const int wm = wave & 1, wn = wave >> 1;

  f32x4 acc[4][4];
#pragma unroll
  for (int i = 0; i < 4; i++)
#pragma unroll
    for (int j = 0; j < 4; j++) acc[i][j] = (f32x4){0.f, 0.f, 0.f, 0.f};

  const int r0 = t >> 2;
  const int c0 = (t & 3) * 8;
  const unsigned short* Ag0 = Abf + ((size_t)bm * 128 + r0) * 1024 + c0;
  const unsigned short* Ag1 = Abf + ((size_t)bm * 128 + 64 + r0) * 1024 + c0;
  const unsigned short* Bg0 = Bt + ((size_t)bn * 128 + r0) * 1024 + c0;
  const unsigned short* Bg1 = Bt + ((size_t)bn * 128 + 64 + r0) * 1024 + c0;
  unsigned short* Al0 = &As[t * 8];
  unsigned short* Al1 = &As[(256 + t) * 8];
  unsigned short* Bl0 = &Bs[t * 8];
  unsigned short* Bl1 = &Bs[(256 + t) * 8];

  for (int kk = 0; kk < 1024; kk += 32) {
    async16(Ag0 + kk, Al0);
    async16(Ag1 + kk, Al1);
    async16(Bg0 + kk, Bl0);
    async16(Bg1 + kk, Bl1);
    __syncthreads();
    bf16x8 af[4], bv[4];
#pragma unroll
    for (int i = 0; i < 4; i++)
      af[i] = *(const bf16x8*)&As[(wm * 64 + i * 16 + lo) * 32 + q * 8];
#pragma unroll
    for (int j = 0; j < 4; j++)
      bv[j] = *(const bf16x8*)&Bs[(wn * 64 + j * 16 + lo) * 32 + q * 8];
#pragma unroll
    for (int i = 0; i < 4; i++)
#pragma unroll
      for (int j = 0; j < 4; j++)
        acc[i][j] = __builtin_amdgcn_mfma_f32_16x16x32_bf16(af[i], bv[j], acc[i][j], 0, 0, 0);
    __syncthreads();
  }

#pragma unroll
  for (int j = 0; j < 4; j++) {
    const int col = bn * 128 + wn * 64 + j * 16 + lo;   // 0..511
    const float bb = (col < 256) ? bmu[col] : blv[col - 256];
    float* dst = (col < 256) ? (out + col) : (out + 65536 + (col - 256));
#pragma unroll
    for (int i = 0; i < 4; i++) {
#pragma unroll
      for (int r = 0; r < 4; r++) {
        const int row = bm * 128 + wm * 64 + i * 16 + q * 4 + r;
        dst[(size_t)row * 256] = acc[i][j][r] + bb;
      }
    }
  }
}

// ---------------- launcher ----------------
extern "C" void kernel_launch(void* const* d_in, const int* in_sizes, int n_in,
                              void* d_out, int out_size, void* d_ws, size_t ws_size,
                              hipStream_t stream) {
  const float* decoder = (const float*)d_in[0];
  const float* targets = (const float*)d_in[1];
  const float* W_proj = (const float*)d_in[2];
  const float* b_proj = (const float*)d_in[3];
  const float* a_raw = (const float*)d_in[4];
  const float* W_out = (const float*)d_in[5];
  const float* b_out = (const float*)d_in[6];
  const float* W_mu = (const float*)d_in[7];
  const float* b_mu = (const float*)d_in[8];
  const float* W_lv = (const float*)d_in[9];
  const float* b_lv = (const float*)d_in[10];
  float* out = (float*)d_out;

  char* ws = (char*)d_ws;
  unsigned short* WT = (unsigned short*)(ws + 134217728);         // 2097152 B
  float* avec = (float*)(ws + 136314880);                         // 4096 B
  float* gvec = (float*)(ws + 136318976);                         // 4096 B
  float* a128v = (float*)(ws + 136323072);                        // 4096 B
  float* DredP = (float*)(ws + 136327168);                        // 2097152 B -> end 138424320
  // low workspace region:
  unsigned short* hTbf = (unsigned short*)ws;                     // 524288 B
  unsigned short* ybf = (unsigned short*)(ws + 524288);           // 524288 B
  unsigned short* WoutT = (unsigned short*)(ws + 1048576);        // 2097152 B
  unsigned short* WcatT = (unsigned short*)(ws + 3145728);        // 1048576 B

  prep_kernel<<<dim3(16, 16, 5), 256, 0, stream>>>(W_proj, a_raw, W_out, W_mu, W_lv,
                                                   WT, avec, gvec, a128v, WoutT, WcatT);
  gemm_seg_kernel<<<256, 512, 0, stream>>>(targets, decoder, WT, avec, gvec, b_proj, DredP);
  state_kernel<<<32, 256, 0, stream>>>(DredP, a128v, hTbf);
  head1_kernel<<<dim3(2, 8), 256, 0, stream>>>(hTbf, WoutT, b_out, ybf);
  head2_kernel<<<dim3(2, 4), 256, 0, stream>>>(ybf, WcatT, b_mu, b_lv, out);
}